// Round 1
// baseline (1236.318 us; speedup 1.0000x reference)
//
#include <hip/hip_runtime.h>

// ---------------- CSR build kernels ----------------

__global__ void k_count(const int* __restrict__ dst, int* __restrict__ cnt, int E) {
    int i = blockIdx.x * 256 + threadIdx.x;
    if (i < E) atomicAdd(&cnt[dst[i]], 1);
}

__global__ void k_scan1(const int* __restrict__ cnt, int* __restrict__ partial, int N) {
    __shared__ int sm[256];
    int idx = blockIdx.x * 256 + threadIdx.x;
    sm[threadIdx.x] = (idx < N) ? cnt[idx] : 0;
    __syncthreads();
    for (int s = 128; s > 0; s >>= 1) {
        if (threadIdx.x < s) sm[threadIdx.x] += sm[threadIdx.x + s];
        __syncthreads();
    }
    if (threadIdx.x == 0) partial[blockIdx.x] = sm[0];
}

__global__ void k_scan2(int* __restrict__ partial, int nb) {
    __shared__ int sm[512];
    int t = threadIdx.x;
    sm[t] = (t < nb) ? partial[t] : 0;
    __syncthreads();
    for (int off = 1; off < 512; off <<= 1) {
        int v = (t >= off) ? sm[t - off] : 0;
        __syncthreads();
        sm[t] += v;
        __syncthreads();
    }
    if (t < nb) partial[t] = (t == 0) ? 0 : sm[t - 1];  // exclusive
}

__global__ void k_scan3(const int* __restrict__ cnt, const int* __restrict__ partial,
                        int* __restrict__ row_off, int* __restrict__ cursor,
                        float* __restrict__ invdeg, int N, int E) {
    __shared__ int sm[256];
    int idx = blockIdx.x * 256 + threadIdx.x;
    int v = (idx < N) ? cnt[idx] : 0;
    sm[threadIdx.x] = v;
    __syncthreads();
    for (int off = 1; off < 256; off <<= 1) {
        int u = (threadIdx.x >= off) ? sm[threadIdx.x - off] : 0;
        __syncthreads();
        sm[threadIdx.x] += u;
        __syncthreads();
    }
    if (idx < N) {
        int excl = partial[blockIdx.x] + sm[threadIdx.x] - v;
        row_off[idx] = excl;
        cursor[idx] = excl;
        invdeg[idx] = 1.0f / (float)((v > 1) ? v : 1);
    }
    if (idx == 0) row_off[N] = E;
}

__global__ void k_scatter(const int* __restrict__ dst, int* __restrict__ cursor,
                          int* __restrict__ eidx, int E) {
    int i = blockIdx.x * 256 + threadIdx.x;
    if (i < E) {
        int p = atomicAdd(&cursor[dst[i]], 1);
        eidx[p] = i;
    }
}

// ---------------- embedding gather ----------------

__global__ void k_emb(const int* __restrict__ gt, const float* __restrict__ emb,
                      float* __restrict__ h0, int N) {
    int i = blockIdx.x * 256 + threadIdx.x;
    if (i < N * 64) {
        int n = i >> 6, f = i & 63;
        h0[i] = emb[(gt[n] << 6) | f];
    }
}

// ---------------- edge aggregation (wave per node) ----------------
// hN[n] = (1/max(deg,1)) * sum_{e: dst[e]==n} leaky_relu(g[src[e]] + W1b @ w_edge[e])

__global__ __launch_bounds__(256)
void k_edge(int N, int fi,
            const int* __restrict__ row_off, const int* __restrict__ eidx,
            const int* __restrict__ src,
            const float* __restrict__ sidx, const float* __restrict__ didx,
            const float* __restrict__ rev,
            const float* __restrict__ g,      // [N,128]
            const float* __restrict__ W1,     // [128, fi+3]
            const float* __restrict__ invdeg,
            float* __restrict__ hN)           // [N,128]
{
    const int lane = threadIdx.x & 63;
    const int wid = (blockIdx.x * blockDim.x + threadIdx.x) >> 6;
    const int nw = (gridDim.x * blockDim.x) >> 6;
    const int ldw1 = fi + 3;
    const float* wr0 = W1 + (size_t)lane * ldw1 + fi;
    const float* wr1 = W1 + (size_t)(lane + 64) * ldw1 + fi;
    const float w00 = wr0[0], w01 = wr0[1], w02 = wr0[2];
    const float w10 = wr1[0], w11 = wr1[1], w12 = wr1[2];

    for (int n = wid; n < N; n += nw) {
        const int beg = row_off[n], end = row_off[n + 1];
        float acc0 = 0.f, acc1 = 0.f;
        for (int p = beg; p < end; ++p) {
            const int e = eidx[p];
            const int s = src[e];
            const float si = sidx[e], di = didx[e], rv = rev[e];
            const float* gr = g + ((size_t)s << 7);
            float v0 = gr[lane] + w00 * si + w01 * di + w02 * rv;
            float v1 = gr[lane + 64] + w10 * si + w11 * di + w12 * rv;
            acc0 += (v0 > 0.f) ? v0 : 0.01f * v0;
            acc1 += (v1 > 0.f) ? v1 : 0.01f * v1;
        }
        const float inv = invdeg[n];
        hN[((size_t)n << 7) + lane] = acc0 * inv;
        hN[((size_t)n << 7) + lane + 64] = acc1 * inv;
    }
}

// ---------------- fp32 GEMM: C[M,O] = A[M,K] @ W[O,K]^T (+bias, act) ----------------
// A is a virtual concat: k < split -> A1 (stride lda1), else A2 (stride lda2, col k-split).
// Tiles: 64 rows x O cols per block, 256 threads, BK=32.

template <int JN>
__global__ __launch_bounds__(256)
void k_gemm(int M, int K, int split,
            const float* __restrict__ A1, int lda1,
            const float* __restrict__ A2, int lda2,
            const float* __restrict__ W, int ldw,
            const float* __restrict__ bias,
            float* __restrict__ C, int ldc, int act)
{
    constexpr int O = JN * 32;
    __shared__ __align__(16) float As[32 * 68];        // [kk][row], stride 68 keeps 16B align + bank spread
    __shared__ __align__(16) float Wsub[32 * (O + 1)]; // [kk][col], stride O+1
    const int t = threadIdx.x;
    const int c = t & 31;
    const int rb = t >> 5;
    const int m0 = blockIdx.x * 64;

    float acc[8][JN];
#pragma unroll
    for (int i = 0; i < 8; i++)
#pragma unroll
        for (int j = 0; j < JN; j++) acc[i][j] = 0.f;

    const int nkt = K >> 5;
    for (int kt = 0; kt < nkt; ++kt) {
        const int k0 = kt << 5;
        const float* A;
        int lda, kof;
        if (k0 < split) { A = A1; lda = lda1; kof = k0; }
        else            { A = A2; lda = lda2; kof = k0 - split; }
        // A tile: 64 rows x 32 k, 512 float4, 2 per thread; store transposed [kk][row]
#pragma unroll
        for (int q = 0; q < 2; q++) {
            int f4 = t + 256 * q;
            int row = f4 >> 3;
            int kk4 = (f4 & 7) << 2;
            int m = m0 + row;
            float4 v = make_float4(0.f, 0.f, 0.f, 0.f);
            if (m < M) v = *(const float4*)(A + (size_t)m * lda + kof + kk4);
            As[(kk4 + 0) * 68 + row] = v.x;
            As[(kk4 + 1) * 68 + row] = v.y;
            As[(kk4 + 2) * 68 + row] = v.z;
            As[(kk4 + 3) * 68 + row] = v.w;
        }
        // W tile: O rows x 32 k, scalar loads (ldw may be odd, e.g. 67/131)
#pragma unroll
        for (int q = 0; q < JN * 4; q++) {
            int idx = t + 256 * q;
            int kk = idx & 31;
            int cc = idx >> 5;
            Wsub[kk * (O + 1) + cc] = W[(size_t)cc * ldw + k0 + kk];
        }
        __syncthreads();
#pragma unroll 8
        for (int kk = 0; kk < 32; kk++) {
            float4 a0 = *(const float4*)&As[kk * 68 + rb * 8];
            float4 a1 = *(const float4*)&As[kk * 68 + rb * 8 + 4];
            float a[8] = {a0.x, a0.y, a0.z, a0.w, a1.x, a1.y, a1.z, a1.w};
            float b[JN];
#pragma unroll
            for (int j = 0; j < JN; j++) b[j] = Wsub[kk * (O + 1) + c + 32 * j];
#pragma unroll
            for (int i = 0; i < 8; i++)
#pragma unroll
                for (int j = 0; j < JN; j++) acc[i][j] = fmaf(a[i], b[j], acc[i][j]);
        }
        __syncthreads();
    }
#pragma unroll
    for (int i = 0; i < 8; i++) {
        int m = m0 + rb * 8 + i;
        if (m < M) {
#pragma unroll
            for (int j = 0; j < JN; j++) {
                float v = acc[i][j];
                if (bias) v += bias[c + 32 * j];
                if (act) v = fmaxf(v, 0.f);
                C[(size_t)m * ldc + c + 32 * j] = v;
            }
        }
    }
}

// ---------------- launcher ----------------

extern "C" void kernel_launch(void* const* d_in, const int* in_sizes, int n_in,
                              void* d_out, int out_size, void* d_ws, size_t ws_size,
                              hipStream_t stream)
{
    const int N = in_sizes[0];
    const int E = in_sizes[1];
    const int* gate = (const int*)d_in[0];
    const int* src = (const int*)d_in[1];
    const int* dst = (const int*)d_in[2];
    const float* sidx = (const float*)d_in[3];
    const float* didx = (const float*)d_in[4];
    const float* rev = (const float*)d_in[5];
    const float* emb = (const float*)d_in[6];
    const float* w1[5] = {(const float*)d_in[7], (const float*)d_in[10], (const float*)d_in[13],
                          (const float*)d_in[16], (const float*)d_in[19]};
    const float* w2[5] = {(const float*)d_in[8], (const float*)d_in[11], (const float*)d_in[14],
                          (const float*)d_in[17], (const float*)d_in[20]};
    const float* b2[5] = {(const float*)d_in[9], (const float*)d_in[12], (const float*)d_in[15],
                          (const float*)d_in[18], (const float*)d_in[21]};

    char* ws = (char*)d_ws;
    size_t off = 0;
    auto alloc = [&](size_t bytes) {
        void* p = ws + off;
        off = (off + bytes + 255) & ~(size_t)255;
        return p;
    };
    float* bufA = (float*)alloc((size_t)N * 128 * 4);
    float* bufB = (float*)alloc((size_t)N * 128 * 4);
    float* hN = (float*)alloc((size_t)N * 128 * 4);
    int* cnt = (int*)alloc((size_t)N * 4);
    int* row_off = (int*)alloc((size_t)(N + 1) * 4);
    int* cursor = (int*)alloc((size_t)N * 4);
    int* eidx = (int*)alloc((size_t)E * 4);
    int* partial = (int*)alloc(512 * 4);
    float* invd = (float*)alloc((size_t)N * 4);

    hipMemsetAsync(cnt, 0, (size_t)N * 4, stream);
    k_count<<<dim3((E + 255) / 256), dim3(256), 0, stream>>>(dst, cnt, E);
    const int nb = (N + 255) / 256;
    k_scan1<<<dim3(nb), dim3(256), 0, stream>>>(cnt, partial, N);
    k_scan2<<<dim3(1), dim3(512), 0, stream>>>(partial, nb);
    k_scan3<<<dim3(nb), dim3(256), 0, stream>>>(cnt, partial, row_off, cursor, invd, N, E);
    k_scatter<<<dim3((E + 255) / 256), dim3(256), 0, stream>>>(dst, cursor, eidx, E);
    k_emb<<<dim3((N * 64 + 255) / 256), dim3(256), 0, stream>>>(gate, emb, bufA, N);

    float* hcur = bufA;
    float* hnxt = bufB;
    const int fis[5] = {64, 128, 128, 128, 128};
    const int gemmGrid = (N + 63) / 64;
    for (int l = 0; l < 5; ++l) {
        const int fi = fis[l];
        const int ld_h = (l == 0) ? 64 : 128;
        float* g = hnxt;
        // g = h @ W1a^T
        k_gemm<4><<<dim3(gemmGrid), dim3(256), 0, stream>>>(
            N, fi, fi, hcur, ld_h, (const float*)nullptr, 0, w1[l], fi + 3,
            (const float*)nullptr, g, 128, 0);
        // hN = mean-aggregate(leaky(g[src] + W1b @ w_edge))
        k_edge<<<dim3((N + 3) / 4), dim3(256), 0, stream>>>(
            N, fi, row_off, eidx, src, sidx, didx, rev, g, w1[l], invd, hN);
        // h' = act([h, hN] @ W2^T + b2)
        if (l < 4) {
            k_gemm<4><<<dim3(gemmGrid), dim3(256), 0, stream>>>(
                N, fi + 128, fi, hcur, ld_h, hN, 128, w2[l], fi + 128, b2[l], hnxt, 128, 1);
        } else {
            k_gemm<2><<<dim3(gemmGrid), dim3(256), 0, stream>>>(
                N, fi + 128, fi, hcur, ld_h, hN, 128, w2[l], fi + 128, b2[l], (float*)d_out, 64, 0);
        }
        float* tmp = hcur;
        hcur = hnxt;
        hnxt = tmp;
    }
}

// Round 2
// 723.871 us; speedup vs baseline: 1.7079x; 1.7079x over previous
//
#include <hip/hip_runtime.h>

typedef __attribute__((ext_vector_type(8))) short short8;
typedef __attribute__((ext_vector_type(4))) float f32x4;
typedef unsigned short u16;

__device__ __forceinline__ u16 f2bf(float f) {
    unsigned u = __float_as_uint(f);
    unsigned r = ((u >> 16) & 1) + 0x7FFFu;
    return (u16)((u + r) >> 16);
}

__device__ __forceinline__ void gload_lds16(const void* g, void* l) {
    __builtin_amdgcn_global_load_lds((const __attribute__((address_space(1))) unsigned int*)g,
                                     (__attribute__((address_space(3))) unsigned int*)l,
                                     16, 0, 0);
}

// ---------------- CSR build kernels ----------------

__global__ void k_count(const int* __restrict__ dst, int* __restrict__ cnt, int E) {
    int i = blockIdx.x * 256 + threadIdx.x;
    if (i < E) atomicAdd(&cnt[dst[i]], 1);
}

__global__ void k_scan1(const int* __restrict__ cnt, int* __restrict__ partial, int N) {
    __shared__ int sm[256];
    int idx = blockIdx.x * 256 + threadIdx.x;
    sm[threadIdx.x] = (idx < N) ? cnt[idx] : 0;
    __syncthreads();
    for (int s = 128; s > 0; s >>= 1) {
        if (threadIdx.x < s) sm[threadIdx.x] += sm[threadIdx.x + s];
        __syncthreads();
    }
    if (threadIdx.x == 0) partial[blockIdx.x] = sm[0];
}

__global__ void k_scan2(int* __restrict__ partial, int nb) {
    __shared__ int sm[512];
    int t = threadIdx.x;
    sm[t] = (t < nb) ? partial[t] : 0;
    __syncthreads();
    for (int off = 1; off < 512; off <<= 1) {
        int v = (t >= off) ? sm[t - off] : 0;
        __syncthreads();
        sm[t] += v;
        __syncthreads();
    }
    if (t < nb) partial[t] = (t == 0) ? 0 : sm[t - 1];  // exclusive
}

__global__ void k_scan3(const int* __restrict__ cnt, const int* __restrict__ partial,
                        int* __restrict__ row_off, int* __restrict__ cursor,
                        float* __restrict__ invdeg, int N, int E) {
    __shared__ int sm[256];
    int idx = blockIdx.x * 256 + threadIdx.x;
    int v = (idx < N) ? cnt[idx] : 0;
    sm[threadIdx.x] = v;
    __syncthreads();
    for (int off = 1; off < 256; off <<= 1) {
        int u = (threadIdx.x >= off) ? sm[threadIdx.x - off] : 0;
        __syncthreads();
        sm[threadIdx.x] += u;
        __syncthreads();
    }
    if (idx < N) {
        int excl = partial[blockIdx.x] + sm[threadIdx.x] - v;
        row_off[idx] = excl;
        cursor[idx] = excl;
        invdeg[idx] = 1.0f / (float)((v > 1) ? v : 1);
    }
    if (idx == 0) row_off[N] = E;
}

__global__ void k_scatter(const int* __restrict__ dst, int* __restrict__ cursor,
                          int* __restrict__ eidx, int E) {
    int i = blockIdx.x * 256 + threadIdx.x;
    if (i < E) {
        int p = atomicAdd(&cursor[dst[i]], 1);
        eidx[p] = i;
    }
}

// ---------------- embedding gather (bf16 out) ----------------

__global__ void k_emb(const int* __restrict__ gt, const float* __restrict__ emb,
                      u16* __restrict__ h0, int N) {
    int i = blockIdx.x * 256 + threadIdx.x;
    if (i < N * 64) {
        int n = i >> 6, f = i & 63;
        h0[i] = f2bf(emb[(gt[n] << 6) | f]);
    }
}

// ---------------- weight fp32 -> bf16 dense conversion ----------------

struct WDesc {
    const float* src[10];
    u16* dst[10];
    int scols[10];
    int dcols[10];
    int n[10];
};

__global__ void k_wconv(WDesc d) {
    int seg = blockIdx.y;
    int idx = blockIdx.x * 256 + threadIdx.x;
    if (idx < d.n[seg]) {
        int dc = d.dcols[seg];
        int r = idx / dc, c = idx % dc;
        d.dst[seg][idx] = f2bf(d.src[seg][r * d.scols[seg] + c]);
    }
}

// ---------------- edge aggregation (wave per node), fp32 math, bf16 hN ----------------

__global__ __launch_bounds__(256)
void k_edge(int N, int fi,
            const int* __restrict__ row_off, const int* __restrict__ eidx,
            const int* __restrict__ src,
            const float* __restrict__ sidx, const float* __restrict__ didx,
            const float* __restrict__ rev,
            const float* __restrict__ g,      // [N,128] fp32
            const float* __restrict__ W1,     // [128, fi+3] fp32 original
            const float* __restrict__ invdeg,
            u16* __restrict__ hN)             // [N,128] bf16
{
    const int lane = threadIdx.x & 63;
    const int wid = (blockIdx.x * blockDim.x + threadIdx.x) >> 6;
    const int nw = (gridDim.x * blockDim.x) >> 6;
    const int ldw1 = fi + 3;
    const float* wr0 = W1 + (size_t)lane * ldw1 + fi;
    const float* wr1 = W1 + (size_t)(lane + 64) * ldw1 + fi;
    const float w00 = wr0[0], w01 = wr0[1], w02 = wr0[2];
    const float w10 = wr1[0], w11 = wr1[1], w12 = wr1[2];

    for (int n = wid; n < N; n += nw) {
        const int beg = row_off[n], end = row_off[n + 1];
        float acc0 = 0.f, acc1 = 0.f;
        for (int p = beg; p < end; ++p) {
            const int e = eidx[p];
            const int s = src[e];
            const float si = sidx[e], di = didx[e], rv = rev[e];
            const float* gr = g + ((size_t)s << 7);
            float v0 = gr[lane] + w00 * si + w01 * di + w02 * rv;
            float v1 = gr[lane + 64] + w10 * si + w11 * di + w12 * rv;
            acc0 += (v0 > 0.f) ? v0 : 0.01f * v0;
            acc1 += (v1 > 0.f) ? v1 : 0.01f * v1;
        }
        const float inv = invdeg[n];
        hN[((size_t)n << 7) + lane] = f2bf(acc0 * inv);
        hN[((size_t)n << 7) + lane + 64] = f2bf(acc1 * inv);
    }
}

// ---------------- bf16 MFMA GEMM ----------------
// C[M,O] = A[M,K] @ W[O,K]^T (+bias, relu).  A virtual concat at SPLIT (A1/A2 bf16).
// Block: 128 rows x O cols, 256 threads = 4 waves (2x2).
// W fully LDS-resident [O][K+8] (pad kills stride-K bank conflict).
// A staged per K-step [128][32] linear via global_load_lds width=16.

template<int K, int O, int SPLIT, int BIAS, int RELU, int OUTBF>
__global__ __launch_bounds__(256)
void k_mfma(int M,
            const u16* __restrict__ A1, int lda1,
            const u16* __restrict__ A2, int lda2,
            const u16* __restrict__ Wb,     // [O][K] dense bf16
            const float* __restrict__ bias,
            void* __restrict__ Cout, int ldc)
{
    constexpr int KP = K + 8;
    constexpr int NF = O / 32;   // N-frags per wave
    constexpr int WC = O / 2;    // cols per wave
    __shared__ __align__(16) u16 Wlds[O * KP];
    __shared__ __align__(16) u16 Atile[128 * 32];

    const int t = threadIdx.x;
    const int m0 = blockIdx.x * 128;
    const int w = t >> 6, l = t & 63;
    const int wm = w & 1, wn = w >> 1;
    const int lr = l & 15, lh = l >> 4;

    // stage W (L2-resident source)
    for (int idx = t; idx < O * (K / 8); idx += 256) {
        int row = idx / (K / 8), ch = idx % (K / 8);
        uint4 v = *(const uint4*)(Wb + (size_t)row * K + ch * 8);
        *(uint4*)(&Wlds[row * KP + ch * 8]) = v;
    }

    f32x4 acc[4][NF];
#pragma unroll
    for (int mi = 0; mi < 4; mi++)
#pragma unroll
        for (int ni = 0; ni < NF; ni++) acc[mi][ni] = (f32x4){0.f, 0.f, 0.f, 0.f};

    __syncthreads();

    for (int kt = 0; kt < K / 32; ++kt) {
        const int k0 = kt * 32;
        const u16* Asrc;
        int lda, kof;
        if (k0 < SPLIT) { Asrc = A1; lda = lda1; kof = k0; }
        else            { Asrc = A2; lda = lda2; kof = k0 - SPLIT; }
#pragma unroll
        for (int q = 0; q < 2; ++q) {
            int o = q * 4096 + t * 16;        // byte offset in Atile
            int row = o >> 6, cb = o & 63;
            int m = m0 + row;
            m = (m < M) ? m : (M - 1);        // clamp tail rows (results discarded on store)
            gload_lds16(Asrc + (size_t)m * lda + kof + (cb >> 1), (void*)(Atile + (o >> 1)));
        }
        __syncthreads();   // compiler drains vmcnt before barrier

        short8 a[4], b[NF];
#pragma unroll
        for (int mi = 0; mi < 4; mi++)
            a[mi] = *(const short8*)(Atile + (wm * 64 + mi * 16 + lr) * 32 + lh * 8);
#pragma unroll
        for (int ni = 0; ni < NF; ni++)
            b[ni] = *(const short8*)(Wlds + (size_t)(wn * WC + ni * 16 + lr) * KP + k0 + lh * 8);
#pragma unroll
        for (int mi = 0; mi < 4; mi++)
#pragma unroll
            for (int ni = 0; ni < NF; ni++)
                acc[mi][ni] = __builtin_amdgcn_mfma_f32_16x16x32_bf16(a[mi], b[ni], acc[mi][ni], 0, 0, 0);
        __syncthreads();   // before next stage overwrites Atile
    }

    // epilogue: D row = (lane>>4)*4 + reg, col = lane&15  [m89-verified mapping]
    float bv[NF];
#pragma unroll
    for (int ni = 0; ni < NF; ni++)
        bv[ni] = BIAS ? bias[wn * WC + ni * 16 + lr] : 0.f;
#pragma unroll
    for (int mi = 0; mi < 4; mi++) {
#pragma unroll
        for (int i = 0; i < 4; i++) {
            int row = m0 + wm * 64 + mi * 16 + lh * 4 + i;
            if (row < M) {
#pragma unroll
                for (int ni = 0; ni < NF; ni++) {
                    float v = acc[mi][ni][i] + bv[ni];
                    if (RELU) v = fmaxf(v, 0.f);
                    int col = wn * WC + ni * 16 + lr;
                    if (OUTBF) ((u16*)Cout)[(size_t)row * ldc + col] = f2bf(v);
                    else       ((float*)Cout)[(size_t)row * ldc + col] = v;
                }
            }
        }
    }
}

// ---------------- launcher ----------------

extern "C" void kernel_launch(void* const* d_in, const int* in_sizes, int n_in,
                              void* d_out, int out_size, void* d_ws, size_t ws_size,
                              hipStream_t stream)
{
    const int N = in_sizes[0];
    const int E = in_sizes[1];
    const int* gate = (const int*)d_in[0];
    const int* src = (const int*)d_in[1];
    const int* dst = (const int*)d_in[2];
    const float* sidx = (const float*)d_in[3];
    const float* didx = (const float*)d_in[4];
    const float* rev = (const float*)d_in[5];
    const float* emb = (const float*)d_in[6];
    const float* w1[5] = {(const float*)d_in[7], (const float*)d_in[10], (const float*)d_in[13],
                          (const float*)d_in[16], (const float*)d_in[19]};
    const float* w2[5] = {(const float*)d_in[8], (const float*)d_in[11], (const float*)d_in[14],
                          (const float*)d_in[17], (const float*)d_in[20]};
    const float* b2[5] = {(const float*)d_in[9], (const float*)d_in[12], (const float*)d_in[15],
                          (const float*)d_in[18], (const float*)d_in[21]};

    char* ws = (char*)d_ws;
    size_t off = 0;
    auto alloc = [&](size_t bytes) {
        void* p = ws + off;
        off = (off + bytes + 255) & ~(size_t)255;
        return p;
    };
    u16* hb0 = (u16*)alloc((size_t)N * 128 * 2);
    u16* hb1 = (u16*)alloc((size_t)N * 128 * 2);
    u16* hN = (u16*)alloc((size_t)N * 128 * 2);
    float* g = (float*)alloc((size_t)N * 128 * 4);
    int* cnt = (int*)alloc((size_t)N * 4);
    int* row_off = (int*)alloc((size_t)(N + 1) * 4);
    int* cursor = (int*)alloc((size_t)N * 4);
    int* eidx = (int*)alloc((size_t)E * 4);
    int* partial = (int*)alloc(512 * 4);
    float* invd = (float*)alloc((size_t)N * 4);
    u16* w1b[5];
    u16* w2b[5];
    const int fis[5] = {64, 128, 128, 128, 128};
    for (int i = 0; i < 5; i++) w1b[i] = (u16*)alloc((size_t)128 * fis[i] * 2);
    for (int i = 0; i < 5; i++) {
        int fo = (i == 4) ? 64 : 128;
        w2b[i] = (u16*)alloc((size_t)fo * (fis[i] + 128) * 2);
    }

    // weight conversions (one launch)
    WDesc wd;
    for (int i = 0; i < 5; i++) {
        wd.src[i] = w1[i]; wd.dst[i] = w1b[i];
        wd.scols[i] = fis[i] + 3; wd.dcols[i] = fis[i]; wd.n[i] = 128 * fis[i];
        int fo = (i == 4) ? 64 : 128;
        wd.src[5 + i] = w2[i]; wd.dst[5 + i] = w2b[i];
        wd.scols[5 + i] = fis[i] + 128; wd.dcols[5 + i] = fis[i] + 128;
        wd.n[5 + i] = fo * (fis[i] + 128);
    }
    k_wconv<<<dim3(128, 10), dim3(256), 0, stream>>>(wd);

    hipMemsetAsync(cnt, 0, (size_t)N * 4, stream);
    k_count<<<dim3((E + 255) / 256), dim3(256), 0, stream>>>(dst, cnt, E);
    const int nb = (N + 255) / 256;
    k_scan1<<<dim3(nb), dim3(256), 0, stream>>>(cnt, partial, N);
    k_scan2<<<dim3(1), dim3(512), 0, stream>>>(partial, nb);
    k_scan3<<<dim3(nb), dim3(256), 0, stream>>>(cnt, partial, row_off, cursor, invd, N, E);
    k_scatter<<<dim3((E + 255) / 256), dim3(256), 0, stream>>>(dst, cursor, eidx, E);
    k_emb<<<dim3((N * 64 + 255) / 256), dim3(256), 0, stream>>>(gate, emb, hb0, N);

    u16* hcur = hb0;
    u16* hnxt = hb1;
    const int gg = (N + 127) / 128;
    const int eg = (N + 3) / 4;

    // ---- layer 1 (fi=64) ----
    k_mfma<64, 128, 64, 0, 0, 0><<<dim3(gg), dim3(256), 0, stream>>>(
        N, hcur, 64, (const u16*)nullptr, 0, w1b[0], (const float*)nullptr, g, 128);
    k_edge<<<dim3(eg), dim3(256), 0, stream>>>(N, 64, row_off, eidx, src, sidx, didx, rev, g, w1[0], invd, hN);
    k_mfma<192, 128, 64, 1, 1, 1><<<dim3(gg), dim3(256), 0, stream>>>(
        N, hcur, 64, hN, 128, w2b[0], b2[0], hnxt, 128);
    hcur = hb1; hnxt = hb0;

    // ---- layers 2..4 (fi=128) ----
    for (int l = 1; l < 4; ++l) {
        k_mfma<128, 128, 128, 0, 0, 0><<<dim3(gg), dim3(256), 0, stream>>>(
            N, hcur, 128, (const u16*)nullptr, 0, w1b[l], (const float*)nullptr, g, 128);
        k_edge<<<dim3(eg), dim3(256), 0, stream>>>(N, 128, row_off, eidx, src, sidx, didx, rev, g, w1[l], invd, hN);
        k_mfma<256, 128, 128, 1, 1, 1><<<dim3(gg), dim3(256), 0, stream>>>(
            N, hcur, 128, hN, 128, w2b[l], b2[l], hnxt, 128);
        u16* tmp = hcur; hcur = hnxt; hnxt = tmp;
    }

    // ---- layer 5 (fi=128, out 64 fp32, no relu) ----
    k_mfma<128, 128, 128, 0, 0, 0><<<dim3(gg), dim3(256), 0, stream>>>(
        N, hcur, 128, (const u16*)nullptr, 0, w1b[4], (const float*)nullptr, g, 128);
    k_edge<<<dim3(eg), dim3(256), 0, stream>>>(N, 128, row_off, eidx, src, sidx, didx, rev, g, w1[4], invd, hN);
    k_mfma<256, 64, 128, 1, 0, 0><<<dim3(gg), dim3(256), 0, stream>>>(
        N, hcur, 128, hN, 128, w2b[4], b2[4], (float*)d_out, 64);
}

// Round 3
// 528.270 us; speedup vs baseline: 2.3403x; 1.3703x over previous
//
#include <hip/hip_runtime.h>
#include <hip/hip_fp16.h>

typedef __attribute__((ext_vector_type(8))) short short8;
typedef __attribute__((ext_vector_type(4))) float f32x4;
typedef unsigned short u16;

__device__ __forceinline__ u16 f2bf(float f) {
    unsigned u = __float_as_uint(f);
    unsigned r = ((u >> 16) & 1) + 0x7FFFu;
    return (u16)((u + r) >> 16);
}

__device__ __forceinline__ void gload_lds16(const void* g, void* l) {
    __builtin_amdgcn_global_load_lds((const __attribute__((address_space(1))) unsigned int*)g,
                                     (__attribute__((address_space(3))) unsigned int*)l,
                                     16, 0, 0);
}

// ---------------- CSR build kernels ----------------

__global__ void k_count(const int* __restrict__ dst, int* __restrict__ cnt, int E) {
    int i = blockIdx.x * 256 + threadIdx.x;
    if (i < E) atomicAdd(&cnt[dst[i]], 1);
}

__global__ void k_scan1(const int* __restrict__ cnt, int* __restrict__ partial, int N) {
    __shared__ int sm[256];
    int idx = blockIdx.x * 256 + threadIdx.x;
    sm[threadIdx.x] = (idx < N) ? cnt[idx] : 0;
    __syncthreads();
    for (int s = 128; s > 0; s >>= 1) {
        if (threadIdx.x < s) sm[threadIdx.x] += sm[threadIdx.x + s];
        __syncthreads();
    }
    if (threadIdx.x == 0) partial[blockIdx.x] = sm[0];
}

__global__ void k_scan2(int* __restrict__ partial, int nb) {
    __shared__ int sm[512];
    int t = threadIdx.x;
    sm[t] = (t < nb) ? partial[t] : 0;
    __syncthreads();
    for (int off = 1; off < 512; off <<= 1) {
        int v = (t >= off) ? sm[t - off] : 0;
        __syncthreads();
        sm[t] += v;
        __syncthreads();
    }
    if (t < nb) partial[t] = (t == 0) ? 0 : sm[t - 1];  // exclusive
}

__global__ void k_scan3(const int* __restrict__ cnt, const int* __restrict__ partial,
                        int* __restrict__ row_off, int* __restrict__ cursor,
                        float* __restrict__ invdeg, int N, int E) {
    __shared__ int sm[256];
    int idx = blockIdx.x * 256 + threadIdx.x;
    int v = (idx < N) ? cnt[idx] : 0;
    sm[threadIdx.x] = v;
    __syncthreads();
    for (int off = 1; off < 256; off <<= 1) {
        int u = (threadIdx.x >= off) ? sm[threadIdx.x - off] : 0;
        __syncthreads();
        sm[threadIdx.x] += u;
        __syncthreads();
    }
    if (idx < N) {
        int excl = partial[blockIdx.x] + sm[threadIdx.x] - v;
        row_off[idx] = excl;
        cursor[idx] = excl;
        invdeg[idx] = 1.0f / (float)((v > 1) ? v : 1);
    }
    if (idx == 0) row_off[N] = E;
}

// scatter edge payload directly into CSR slots: {src, si, di, rv}
__global__ void k_scatter(const int* __restrict__ dst, const int* __restrict__ src,
                          const float* __restrict__ sidx, const float* __restrict__ didx,
                          const float* __restrict__ rev,
                          int* __restrict__ cursor, int4* __restrict__ payload, int E) {
    int i = blockIdx.x * 256 + threadIdx.x;
    if (i < E) {
        int p = atomicAdd(&cursor[dst[i]], 1);
        int4 v;
        v.x = src[i];
        v.y = __float_as_int(sidx[i]);
        v.z = __float_as_int(didx[i]);
        v.w = __float_as_int(rev[i]);
        payload[p] = v;
    }
}

// ---------------- embedding gather (bf16 out) ----------------

__global__ void k_emb(const int* __restrict__ gt, const float* __restrict__ emb,
                      u16* __restrict__ h0, int N) {
    int i = blockIdx.x * 256 + threadIdx.x;
    if (i < N * 64) {
        int n = i >> 6, f = i & 63;
        h0[i] = f2bf(emb[(gt[n] << 6) | f]);
    }
}

// ---------------- weight fp32 -> bf16 dense conversion ----------------

struct WDesc {
    const float* src[10];
    u16* dst[10];
    int scols[10];
    int dcols[10];
    int n[10];
};

__global__ void k_wconv(WDesc d) {
    int seg = blockIdx.y;
    int idx = blockIdx.x * 256 + threadIdx.x;
    if (idx < d.n[seg]) {
        int dc = d.dcols[seg];
        int r = idx / dc, c = idx % dc;
        d.dst[seg][idx] = f2bf(d.src[seg][r * d.scols[seg] + c]);
    }
}

// ---------------- edge aggregation (wave per node), fp16 g, fp32 math, bf16 hN ----------------
// lane handles feats (2*lane, 2*lane+1): one dword gather per edge per lane.

__global__ __launch_bounds__(256)
void k_edge(int N, int fi,
            const int* __restrict__ row_off, const int4* __restrict__ payload,
            const u16* __restrict__ g,        // [N,128] fp16
            const float* __restrict__ W1,     // [128, fi+3] fp32 original
            const float* __restrict__ invdeg,
            u16* __restrict__ hN)             // [N,128] bf16
{
    const int lane = threadIdx.x & 63;
    const int wid = (blockIdx.x * blockDim.x + threadIdx.x) >> 6;
    const int nw = (gridDim.x * blockDim.x) >> 6;
    const int ldw1 = fi + 3;
    const float* wr0 = W1 + (size_t)(2 * lane) * ldw1 + fi;
    const float* wr1 = W1 + (size_t)(2 * lane + 1) * ldw1 + fi;
    const float w00 = wr0[0], w01 = wr0[1], w02 = wr0[2];
    const float w10 = wr1[0], w11 = wr1[1], w12 = wr1[2];

    for (int n = wid; n < N; n += nw) {
        const int beg = row_off[n], end = row_off[n + 1];
        float acc0 = 0.f, acc1 = 0.f;
        if (beg < end) {
            int4 pl = payload[beg];
            for (int p = beg; p < end; ++p) {
                const int s = pl.x;
                const float si = __int_as_float(pl.y);
                const float di = __int_as_float(pl.z);
                const float rv = __int_as_float(pl.w);
                const unsigned gv = *(const unsigned*)(g + ((size_t)s << 7) + 2 * lane);
                if (p + 1 < end) pl = payload[p + 1];
                const __half2 h2 = *(const __half2*)&gv;
                const float2 f = __half22float2(h2);
                float v0 = f.x + w00 * si + w01 * di + w02 * rv;
                float v1 = f.y + w10 * si + w11 * di + w12 * rv;
                acc0 += (v0 > 0.f) ? v0 : 0.01f * v0;
                acc1 += (v1 > 0.f) ? v1 : 0.01f * v1;
            }
        }
        const float inv = invdeg[n];
        unsigned out = (unsigned)f2bf(acc0 * inv) | ((unsigned)f2bf(acc1 * inv) << 16);
        *(unsigned*)(hN + ((size_t)n << 7) + 2 * lane) = out;
    }
}

// ---------------- bf16 MFMA GEMM ----------------
// C[M,O] = A[M,K] @ W[O,K]^T (+bias, act).  A virtual concat at SPLIT (A1/A2 bf16).
// Block: 128 rows x O cols, 256 threads = 4 waves (2x2).
// OUTDT: 0 = fp32, 1 = bf16, 2 = fp16.

template<int K, int O, int SPLIT, int BIAS, int RELU, int OUTDT>
__global__ __launch_bounds__(256)
void k_mfma(int M,
            const u16* __restrict__ A1, int lda1,
            const u16* __restrict__ A2, int lda2,
            const u16* __restrict__ Wb,     // [O][K] dense bf16
            const float* __restrict__ bias,
            void* __restrict__ Cout, int ldc)
{
    constexpr int KP = K + 8;
    constexpr int NF = O / 32;   // N-frags per wave
    constexpr int WC = O / 2;    // cols per wave
    __shared__ __align__(16) u16 Wlds[O * KP];
    __shared__ __align__(16) u16 Atile[128 * 32];

    const int t = threadIdx.x;
    const int m0 = blockIdx.x * 128;
    const int w = t >> 6, l = t & 63;
    const int wm = w & 1, wn = w >> 1;
    const int lr = l & 15, lh = l >> 4;

    // stage W (L2-resident source)
    for (int idx = t; idx < O * (K / 8); idx += 256) {
        int row = idx / (K / 8), ch = idx % (K / 8);
        uint4 v = *(const uint4*)(Wb + (size_t)row * K + ch * 8);
        *(uint4*)(&Wlds[row * KP + ch * 8]) = v;
    }

    f32x4 acc[4][NF];
#pragma unroll
    for (int mi = 0; mi < 4; mi++)
#pragma unroll
        for (int ni = 0; ni < NF; ni++) acc[mi][ni] = (f32x4){0.f, 0.f, 0.f, 0.f};

    __syncthreads();

    for (int kt = 0; kt < K / 32; ++kt) {
        const int k0 = kt * 32;
        const u16* Asrc;
        int lda, kof;
        if (k0 < SPLIT) { Asrc = A1; lda = lda1; kof = k0; }
        else            { Asrc = A2; lda = lda2; kof = k0 - SPLIT; }
#pragma unroll
        for (int q = 0; q < 2; ++q) {
            int o = q * 4096 + t * 16;        // byte offset in Atile
            int row = o >> 6, cb = o & 63;
            int m = m0 + row;
            m = (m < M) ? m : (M - 1);        // clamp tail rows (results discarded on store)
            gload_lds16(Asrc + (size_t)m * lda + kof + (cb >> 1), (void*)(Atile + (o >> 1)));
        }
        __syncthreads();   // compiler drains vmcnt before barrier

        short8 a[4], b[NF];
#pragma unroll
        for (int mi = 0; mi < 4; mi++)
            a[mi] = *(const short8*)(Atile + (wm * 64 + mi * 16 + lr) * 32 + lh * 8);
#pragma unroll
        for (int ni = 0; ni < NF; ni++)
            b[ni] = *(const short8*)(Wlds + (size_t)(wn * WC + ni * 16 + lr) * KP + k0 + lh * 8);
#pragma unroll
        for (int mi = 0; mi < 4; mi++)
#pragma unroll
            for (int ni = 0; ni < NF; ni++)
                acc[mi][ni] = __builtin_amdgcn_mfma_f32_16x16x32_bf16(a[mi], b[ni], acc[mi][ni], 0, 0, 0);
        __syncthreads();   // before next stage overwrites Atile
    }

    // epilogue: D row = (lane>>4)*4 + reg, col = lane&15
    float bv[NF];
#pragma unroll
    for (int ni = 0; ni < NF; ni++)
        bv[ni] = BIAS ? bias[wn * WC + ni * 16 + lr] : 0.f;
#pragma unroll
    for (int mi = 0; mi < 4; mi++) {
#pragma unroll
        for (int i = 0; i < 4; i++) {
            int row = m0 + wm * 64 + mi * 16 + lh * 4 + i;
            if (row < M) {
#pragma unroll
                for (int ni = 0; ni < NF; ni++) {
                    float v = acc[mi][ni][i] + bv[ni];
                    if (RELU) v = fmaxf(v, 0.f);
                    int col = wn * WC + ni * 16 + lr;
                    if (OUTDT == 1)      ((u16*)Cout)[(size_t)row * ldc + col] = f2bf(v);
                    else if (OUTDT == 2) ((__half*)Cout)[(size_t)row * ldc + col] = __float2half(v);
                    else                 ((float*)Cout)[(size_t)row * ldc + col] = v;
                }
            }
        }
    }
}

// ---------------- launcher ----------------

extern "C" void kernel_launch(void* const* d_in, const int* in_sizes, int n_in,
                              void* d_out, int out_size, void* d_ws, size_t ws_size,
                              hipStream_t stream)
{
    const int N = in_sizes[0];
    const int E = in_sizes[1];
    const int* gate = (const int*)d_in[0];
    const int* src = (const int*)d_in[1];
    const int* dst = (const int*)d_in[2];
    const float* sidx = (const float*)d_in[3];
    const float* didx = (const float*)d_in[4];
    const float* rev = (const float*)d_in[5];
    const float* emb = (const float*)d_in[6];
    const float* w1[5] = {(const float*)d_in[7], (const float*)d_in[10], (const float*)d_in[13],
                          (const float*)d_in[16], (const float*)d_in[19]};
    const float* w2[5] = {(const float*)d_in[8], (const float*)d_in[11], (const float*)d_in[14],
                          (const float*)d_in[17], (const float*)d_in[20]};
    const float* b2[5] = {(const float*)d_in[9], (const float*)d_in[12], (const float*)d_in[15],
                          (const float*)d_in[18], (const float*)d_in[21]};

    char* ws = (char*)d_ws;
    size_t off = 0;
    auto alloc = [&](size_t bytes) {
        void* p = ws + off;
        off = (off + bytes + 255) & ~(size_t)255;
        return p;
    };
    u16* hb0 = (u16*)alloc((size_t)N * 128 * 2);
    u16* hb1 = (u16*)alloc((size_t)N * 128 * 2);
    u16* hN = (u16*)alloc((size_t)N * 128 * 2);
    u16* g = (u16*)alloc((size_t)N * 128 * 2);        // fp16
    int* cnt = (int*)alloc((size_t)N * 4);
    int* row_off = (int*)alloc((size_t)(N + 1) * 4);
    int* cursor = (int*)alloc((size_t)N * 4);
    int4* payload = (int4*)alloc((size_t)E * 16);
    int* partial = (int*)alloc(512 * 4);
    float* invd = (float*)alloc((size_t)N * 4);
    u16* w1b[5];
    u16* w2b[5];
    const int fis[5] = {64, 128, 128, 128, 128};
    for (int i = 0; i < 5; i++) w1b[i] = (u16*)alloc((size_t)128 * fis[i] * 2);
    for (int i = 0; i < 5; i++) {
        int fo = (i == 4) ? 64 : 128;
        w2b[i] = (u16*)alloc((size_t)fo * (fis[i] + 128) * 2);
    }

    // weight conversions (one launch)
    WDesc wd;
    for (int i = 0; i < 5; i++) {
        wd.src[i] = w1[i]; wd.dst[i] = w1b[i];
        wd.scols[i] = fis[i] + 3; wd.dcols[i] = fis[i]; wd.n[i] = 128 * fis[i];
        int fo = (i == 4) ? 64 : 128;
        wd.src[5 + i] = w2[i]; wd.dst[5 + i] = w2b[i];
        wd.scols[5 + i] = fis[i] + 128; wd.dcols[5 + i] = fis[i] + 128;
        wd.n[5 + i] = fo * (fis[i] + 128);
    }
    k_wconv<<<dim3(128, 10), dim3(256), 0, stream>>>(wd);

    hipMemsetAsync(cnt, 0, (size_t)N * 4, stream);
    k_count<<<dim3((E + 255) / 256), dim3(256), 0, stream>>>(dst, cnt, E);
    const int nb = (N + 255) / 256;
    k_scan1<<<dim3(nb), dim3(256), 0, stream>>>(cnt, partial, N);
    k_scan2<<<dim3(1), dim3(512), 0, stream>>>(partial, nb);
    k_scan3<<<dim3(nb), dim3(256), 0, stream>>>(cnt, partial, row_off, cursor, invd, N, E);
    k_scatter<<<dim3((E + 255) / 256), dim3(256), 0, stream>>>(dst, src, sidx, didx, rev, cursor, payload, E);
    k_emb<<<dim3((N * 64 + 255) / 256), dim3(256), 0, stream>>>(gate, emb, hb0, N);

    u16* hcur = hb0;
    u16* hnxt = hb1;
    const int gg = (N + 127) / 128;
    const int eg = (N + 3) / 4;

    // ---- layer 1 (fi=64) ----
    k_mfma<64, 128, 64, 0, 0, 2><<<dim3(gg), dim3(256), 0, stream>>>(
        N, hcur, 64, (const u16*)nullptr, 0, w1b[0], (const float*)nullptr, g, 128);
    k_edge<<<dim3(eg), dim3(256), 0, stream>>>(N, 64, row_off, payload, g, w1[0], invd, hN);
    k_mfma<192, 128, 64, 1, 1, 1><<<dim3(gg), dim3(256), 0, stream>>>(
        N, hcur, 64, hN, 128, w2b[0], b2[0], hnxt, 128);
    hcur = hb1; hnxt = hb0;

    // ---- layers 2..4 (fi=128) ----
    for (int l = 1; l < 4; ++l) {
        k_mfma<128, 128, 128, 0, 0, 2><<<dim3(gg), dim3(256), 0, stream>>>(
            N, hcur, 128, (const u16*)nullptr, 0, w1b[l], (const float*)nullptr, g, 128);
        k_edge<<<dim3(eg), dim3(256), 0, stream>>>(N, 128, row_off, payload, g, w1[l], invd, hN);
        k_mfma<256, 128, 128, 1, 1, 1><<<dim3(gg), dim3(256), 0, stream>>>(
            N, hcur, 128, hN, 128, w2b[l], b2[l], hnxt, 128);
        u16* tmp = hcur; hcur = hnxt; hnxt = tmp;
    }

    // ---- layer 5 (fi=128, out 64 fp32, no relu) ----
    k_mfma<128, 128, 128, 0, 0, 2><<<dim3(gg), dim3(256), 0, stream>>>(
        N, hcur, 128, (const u16*)nullptr, 0, w1b[4], (const float*)nullptr, g, 128);
    k_edge<<<dim3(eg), dim3(256), 0, stream>>>(N, 128, row_off, payload, g, w1[4], invd, hN);
    k_mfma<256, 64, 128, 1, 0, 0><<<dim3(gg), dim3(256), 0, stream>>>(
        N, hcur, 128, hN, 128, w2b[4], b2[4], (float*)d_out, 64);
}